// Round 4
// baseline (111.227 us; speedup 1.0000x reference)
//
#include <hip/hip_runtime.h>

#define N_ROWS 128
#define IN_DIM 1024
#define OUT_DIM 1024

// out[n,o] = max_k(w[o,k] + x[n,k]) + bias[o]   (tropical matmul)
//
// R4: DISCRIMINATING EXPERIMENT — kernel unchanged from R3; launched 4x.
// R1/R2/R3 varied occupancy 4x, LDS traffic 4x, w traffic 4x -> total
// flat at 72.2/72.1/71.8 (inside the poison-fill's +-1.4us noise). The
// kernel never shows in rocprof top-5 (<40us), so dur_us=72 includes the
// 40.5us fill + ~31us unattributed. This round measures the kernel's own
// device time via the marginal cost of 3 extra (idempotent) launches:
//   H2 (kernel ~5us, overhead floor): dur -> 85-90us
//   H1' (kernel ~31us, unmodeled):    dur -> 150-170us
// Launches 2-4 are L2-warm for w -> warm-kernel time = per-extra-launch
// increment. Kernel also becomes visible in top-5 counters.

__global__ __launch_bounds__(256, 4)
void tropical_linear_kernel(const float* __restrict__ x,
                            const float* __restrict__ w,
                            const float* __restrict__ bias,
                            float* __restrict__ out) {
    __shared__ float4 xs[2 * 256];   // 8 KB

    const int tid  = threadIdx.x;
    const int wid  = tid >> 6;       // wave 0..3
    const int lane = tid & 63;
    const int g    = lane & 15;      // k phase 0..15
    const int og   = lane >> 4;      // o group 0..3

    const int bn = blockIdx.x >> 4;  // 64 n-blocks
    const int bo = blockIdx.x & 15;  // 16 o-blocks (idx%8==bo%8 -> same XCD)
    const int n0 = bn * 2;
    const int obase = bo * 64 + wid * 16 + og * 4;

    const float4* __restrict__ x4 = (const float4*)x;

    // ---- stage x tile: 512 float4, 2 per thread, coalesced ----
#pragma unroll
    for (int i = 0; i < 2; ++i) {
        const int idx = tid + i * 256;
        xs[idx] = x4[(size_t)(n0 + (idx >> 8)) * 256 + (idx & 255)];
    }

    // w row pointers (row stride 4096 B > 13-bit imm, so 4 bases; the
    // 16 k-steps per row fold into imm offsets t*256 <= 3840).
    const float4* __restrict__ wp0 = (const float4*)w + (size_t)(obase + 0) * 256 + g;
    const float4* __restrict__ wp1 = (const float4*)w + (size_t)(obase + 1) * 256 + g;
    const float4* __restrict__ wp2 = (const float4*)w + (size_t)(obase + 2) * 256 + g;
    const float4* __restrict__ wp3 = (const float4*)w + (size_t)(obase + 3) * 256 + g;

    // w prologue loads (t=0,1) issued before the barrier: independent of LDS
    float4 wA[4], wB[4];
    wA[0] = wp0[0];  wA[1] = wp1[0];  wA[2] = wp2[0];  wA[3] = wp3[0];
    wB[0] = wp0[16]; wB[1] = wp1[16]; wB[2] = wp2[16]; wB[3] = wp3[16];

    float acc[2][4];
#pragma unroll
    for (int j = 0; j < 2; ++j)
#pragma unroll
        for (int r = 0; r < 4; ++r) acc[j][r] = -3.4e38f;

    __syncthreads();

    const float4* __restrict__ xsg = xs + g;

    float4 xA[2], xB[2];
#pragma unroll
    for (int j = 0; j < 2; ++j) xA[j] = xsg[j * 256];    // t=0

#define TROPIC_STEP(WBUF, XBUF)                                   \
    _Pragma("unroll")                                             \
    for (int j = 0; j < 2; ++j) {                                 \
        const float4 xv = XBUF[j];                                \
        _Pragma("unroll")                                         \
        for (int r = 0; r < 4; ++r) {                             \
            const float s0 = WBUF[r].x + xv.x;                    \
            const float s1 = WBUF[r].y + xv.y;                    \
            const float s2 = WBUF[r].z + xv.z;                    \
            const float s3 = WBUF[r].w + xv.w;                    \
            const float m = fmaxf(fmaxf(s0, s1), s2);             \
            acc[j][r] = fmaxf(fmaxf(m, s3), acc[j][r]);           \
        }                                                         \
    }

    // Steady state: 7 iterations x 2 k-steps; tail handles t=14,15.
#pragma unroll 1
    for (int tt = 0; tt < 7; ++tt) {
        const int t0 = 2 * tt;
        // ---- step t0: consume (wA, xA) ----
#pragma unroll
        for (int j = 0; j < 2; ++j) xB[j] = xsg[j * 256 + (t0 + 1) * 16];
        TROPIC_STEP(wA, xA)
        // reload wA for t0+2 right after last use (2-step lead)
        wA[0] = wp0[(t0 + 2) * 16]; wA[1] = wp1[(t0 + 2) * 16];
        wA[2] = wp2[(t0 + 2) * 16]; wA[3] = wp3[(t0 + 2) * 16];
        // ---- step t1: consume (wB, xB) ----
#pragma unroll
        for (int j = 0; j < 2; ++j) xA[j] = xsg[j * 256 + (t0 + 2) * 16];
        TROPIC_STEP(wB, xB)
        wB[0] = wp0[(t0 + 3) * 16]; wB[1] = wp1[(t0 + 3) * 16];
        wB[2] = wp2[(t0 + 3) * 16]; wB[3] = wp3[(t0 + 3) * 16];
    }
    // ---- tail: t=14 (wA,xA), t=15 (wB,xB) ----
#pragma unroll
    for (int j = 0; j < 2; ++j) xB[j] = xsg[j * 256 + 15 * 16];
    TROPIC_STEP(wA, xA)
    TROPIC_STEP(wB, xB)

#undef TROPIC_STEP

    // ---- reduce across the 16 k-phases (lane bits 0..3) ----
#pragma unroll
    for (int j = 0; j < 2; ++j) {
#pragma unroll
        for (int r = 0; r < 4; ++r) {
            float v = acc[j][r];
            v = fmaxf(v, __shfl_xor(v, 1, 64));
            v = fmaxf(v, __shfl_xor(v, 2, 64));
            v = fmaxf(v, __shfl_xor(v, 4, 64));
            v = fmaxf(v, __shfl_xor(v, 8, 64));
            acc[j][r] = v;
        }
    }

    // After the butterfly all 16 g-lanes in an og group hold identical
    // acc; lanes g<4 each store one float2: j = g&1, col pair pr = g>>1.
    if (g < 4) {
        const int jj = g & 1;        // n-row within tile
        const int pr = g >> 1;       // which float2 column pair
        float2 res = make_float2(0.f, 0.f);
#pragma unroll
        for (int j = 0; j < 2; ++j) {
            if (jj == j) {           // static indices only
                res.x = pr ? acc[j][2] : acc[j][0];
                res.y = pr ? acc[j][3] : acc[j][1];
            }
        }
        const int oc = obase + pr * 2;
        const float2 bv = *(const float2*)&bias[oc];
        res.x += bv.x;
        res.y += bv.y;
        *(float2*)&out[(size_t)(n0 + jj) * OUT_DIM + oc] = res;
    }
}

extern "C" void kernel_launch(void* const* d_in, const int* in_sizes, int n_in,
                              void* d_out, int out_size, void* d_ws, size_t ws_size,
                              hipStream_t stream) {
    const float* x    = (const float*)d_in[0];   // [128,1024]
    const float* w    = (const float*)d_in[1];   // [1024,1024]
    const float* bias = (const float*)d_in[2];   // [1024]
    float* out = (float*)d_out;                  // [128,1024]

    dim3 grid(1024);
    dim3 block(256);
    // 4 identical launches: marginal cost of #2..#4 = kernel device time
    // (idempotent -> output still correct). See R4 header comment.
    for (int rep = 0; rep < 4; ++rep) {
        hipLaunchKernelGGL(tropical_linear_kernel, grid, block, 0, stream,
                           x, w, bias, out);
    }
}

// Round 5
// 86.264 us; speedup vs baseline: 1.2894x; 1.2894x over previous
//
#include <hip/hip_runtime.h>

#define N_ROWS 128
#define IN_DIM 1024
#define OUT_DIM 1024

// out[n,o] = max_k(w[o,k] + x[n,k]) + bias[o]   (tropical matmul)
//
// R5: in-block K-split decouples w-amortization from occupancy.
// R4 measured warm kernel = 13.1 us (marginal of serialized relaunches).
// Pipe balance per wave-step: VALU:LDS:VMEM = 3*n_w*r : 12*n_w : 16*r.
// R3 (n_w=2,r=4) = 24:24:64 -> w-stream-bound: 268 MB via L2 = 8-11 us,
// matching the 13.1. Fix: n_w=8 (w traffic 64 MB) while keeping 16
// waves/CU by splitting K 4-way across the block's 4 waves:
//   block = 4 waves, tile 8n x 16o, wave `wid` owns K-quarter wid*256.
//   Grid 16 n-blocks x 64 o-blocks = 1024 blocks = 4/CU = 16 waves/CU.
// Balance 96:96:64 -> VALU/LDS-limited at the ~2.6 us floor.
// x (8 rows, 32 KB) staged in LDS; per-wave partial maxima combined via
// 2 KB LDS scratch + one barrier. LDS 34 KB x 4 blocks = 136 <= 160.
// VGPR ~111 (acc 32 + x 32 + w dbuf 32) -> 4 blocks/CU legal.
// Same-bo blocks -> same XCD (64%8==0): w resident 512 KB/XCD in L2.

__global__ __launch_bounds__(256, 4)
void tropical_linear_kernel(const float* __restrict__ x,
                            const float* __restrict__ w,
                            const float* __restrict__ bias,
                            float* __restrict__ out) {
    __shared__ float4 xs[8 * 256];     // 32 KB: 8 n-rows x 1024 k
    __shared__ float2 sc[4][64];       // 2 KB: per-wave partial results

    const int tid  = threadIdx.x;
    const int wid  = tid >> 6;       // wave 0..3 = K-quarter
    const int lane = tid & 63;
    const int g    = lane & 15;      // k phase 0..15 within quarter-step
    const int og   = lane >> 4;      // o group 0..3

    const int bn = blockIdx.x >> 6;  // 16 n-blocks
    const int bo = blockIdx.x & 63;  // 64 o-blocks (idx%8==bo%8 -> same XCD)
    const int n0 = bn * 8;
    const int obase = bo * 16 + og * 4;

    const float4* __restrict__ x4 = (const float4*)x;

    // ---- stage x tile: 2048 float4, 8 per thread, coalesced ----
#pragma unroll
    for (int i = 0; i < 8; ++i) {
        const int idx = tid + i * 256;
        xs[idx] = x4[(size_t)(n0 + (idx >> 8)) * 256 + (idx & 255)];
    }

    // w row pointers: row stride 256 f4; quarter offset wid*64 f4 folded in.
    // Loads use static imm offsets s*16 f4 (s=0..3), bytes 0/256/512/768.
    const float4* __restrict__ wp0 = (const float4*)w + (size_t)(obase + 0) * 256 + wid * 64 + g;
    const float4* __restrict__ wp1 = (const float4*)w + (size_t)(obase + 1) * 256 + wid * 64 + g;
    const float4* __restrict__ wp2 = (const float4*)w + (size_t)(obase + 2) * 256 + wid * 64 + g;
    const float4* __restrict__ wp3 = (const float4*)w + (size_t)(obase + 3) * 256 + wid * 64 + g;

    // w prologue (s=0,1) issued before the barrier: independent of LDS
    float4 wA[4], wB[4];
    wA[0] = wp0[0];  wA[1] = wp1[0];  wA[2] = wp2[0];  wA[3] = wp3[0];
    wB[0] = wp0[16]; wB[1] = wp1[16]; wB[2] = wp2[16]; wB[3] = wp3[16];

    float acc[8][4];
#pragma unroll
    for (int j = 0; j < 8; ++j)
#pragma unroll
        for (int r = 0; r < 4; ++r) acc[j][r] = -3.4e38f;

    __syncthreads();

    // per-wave LDS base: column f4 = wid*64 + s*16 + g (imm: j*256 + s*16)
    const float4* __restrict__ xsg = xs + wid * 64 + g;

    float4 xq[8];

#define TROPIC_STEP(WBUF)                                         \
    _Pragma("unroll")                                             \
    for (int j = 0; j < 8; ++j) {                                 \
        const float4 xv = xq[j];                                  \
        _Pragma("unroll")                                         \
        for (int r = 0; r < 4; ++r) {                             \
            const float s0 = WBUF[r].x + xv.x;                    \
            const float s1 = WBUF[r].y + xv.y;                    \
            const float s2 = WBUF[r].z + xv.z;                    \
            const float s3 = WBUF[r].w + xv.w;                    \
            const float m = fmaxf(fmaxf(s0, s1), s2);             \
            acc[j][r] = fmaxf(fmaxf(m, s3), acc[j][r]);           \
        }                                                         \
    }

    // ---- 4 k-steps (this wave's K-quarter), w double-buffered ----
#pragma unroll
    for (int j = 0; j < 8; ++j) xq[j] = xsg[j * 256];            // s=0
    TROPIC_STEP(wA)
    wA[0] = wp0[32]; wA[1] = wp1[32]; wA[2] = wp2[32]; wA[3] = wp3[32];

#pragma unroll
    for (int j = 0; j < 8; ++j) xq[j] = xsg[j * 256 + 16];       // s=1
    TROPIC_STEP(wB)
    wB[0] = wp0[48]; wB[1] = wp1[48]; wB[2] = wp2[48]; wB[3] = wp3[48];

#pragma unroll
    for (int j = 0; j < 8; ++j) xq[j] = xsg[j * 256 + 32];       // s=2
    TROPIC_STEP(wA)

#pragma unroll
    for (int j = 0; j < 8; ++j) xq[j] = xsg[j * 256 + 48];       // s=3
    TROPIC_STEP(wB)

#undef TROPIC_STEP

    // ---- reduce across the 16 k-phases (lane bits 0..3) ----
#pragma unroll
    for (int j = 0; j < 8; ++j) {
#pragma unroll
        for (int r = 0; r < 4; ++r) {
            float v = acc[j][r];
            v = fmaxf(v, __shfl_xor(v, 1, 64));
            v = fmaxf(v, __shfl_xor(v, 2, 64));
            v = fmaxf(v, __shfl_xor(v, 4, 64));
            v = fmaxf(v, __shfl_xor(v, 8, 64));
            acc[j][r] = v;
        }
    }

    // ---- write per-wave partials: lane g -> (j = g>>1, pr = g&1) ----
    // (static acc indexing via unrolled predicate chain, rule #20)
    {
        const int jj = g >> 1;
        const int pr = g & 1;
        float2 res = make_float2(-3.4e38f, -3.4e38f);
#pragma unroll
        for (int j = 0; j < 8; ++j) {
            if (jj == j) {
                res.x = pr ? acc[j][2] : acc[j][0];
                res.y = pr ? acc[j][3] : acc[j][1];
            }
        }
        sc[wid][og * 16 + g] = res;
    }
    __syncthreads();

    // ---- combine the 4 K-quarter partials, add bias, store ----
    if (tid < 64) {
        const int me  = tid;
        float2 a = sc[0][me], b = sc[1][me], c = sc[2][me], d = sc[3][me];
        float2 res;
        res.x = fmaxf(fmaxf(a.x, b.x), fmaxf(c.x, d.x));
        res.y = fmaxf(fmaxf(a.y, b.y), fmaxf(c.y, d.y));
        const int ogf = me >> 4;
        const int rem = me & 15;
        const int j   = rem >> 1;
        const int pr  = rem & 1;
        const int o   = bo * 16 + ogf * 4 + pr * 2;
        const float2 bv = *(const float2*)&bias[o];
        res.x += bv.x;
        res.y += bv.y;
        *(float2*)&out[(size_t)(n0 + j) * OUT_DIM + o] = res;
    }
}

extern "C" void kernel_launch(void* const* d_in, const int* in_sizes, int n_in,
                              void* d_out, int out_size, void* d_ws, size_t ws_size,
                              hipStream_t stream) {
    const float* x    = (const float*)d_in[0];   // [128,1024]
    const float* w    = (const float*)d_in[1];   // [1024,1024]
    const float* bias = (const float*)d_in[2];   // [1024]
    float* out = (float*)d_out;                  // [128,1024]

    dim3 grid(1024);
    dim3 block(256);
    hipLaunchKernelGGL(tropical_linear_kernel, grid, block, 0, stream, x, w, bias, out);
}